// Round 11
// baseline (1083.363 us; speedup 1.0000x reference)
//
#include <hip/hip_runtime.h>

#define N_NODES 50000
#define N_EDGES 800000
#define IN_F 10
#define HID 256
#define EMB 128
#define BN_EPS 1e-5f
#define N_SCAN_BLKS ((N_NODES + 255) / 256)  // 196
#define CNT_BLKS (N_EDGES / 256)             // 3125
#define WCONV_ELEMS (4 * HID * HID + 2 * EMB * HID)  // 327680
#define WCONV_BLKS (WCONV_ELEMS / 256)       // 1280
#define SSTRIDE 512
#define NSHARD 8
#define NPART 8
#define PART_SZ (N_NODES / NPART)            // 6250
#define SCAT_BLKS 2048

typedef __attribute__((ext_vector_type(8))) short short8;
typedef __attribute__((ext_vector_type(4))) float floatx4;
typedef __attribute__((ext_vector_type(2))) float floatx2;

__device__ __forceinline__ unsigned short f2bf(float f) {
    unsigned u = __float_as_uint(f);
    unsigned r = (u + 0x7fffu + ((u >> 16) & 1u)) >> 16;
    return (unsigned short)r;
}
__device__ __forceinline__ float bf_lo(unsigned int u) { return __uint_as_float(u << 16); }
__device__ __forceinline__ float bf_hi(unsigned int u) { return __uint_as_float(u & 0xffff0000u); }
__device__ __forceinline__ float bf2f(unsigned short s) { return __uint_as_float(((unsigned)s) << 16); }

// ---------------- fused: degree count + all 6 weight convert/transpose ----------------
__global__ void k_count_wconv(const int* __restrict__ e_dst, int* __restrict__ cnt,
                              const float* __restrict__ wl1, const float* __restrict__ wr1,
                              const float* __restrict__ wl2, const float* __restrict__ wr2,
                              const float* __restrict__ wl3, const float* __restrict__ wr3,
                              unsigned short* __restrict__ wl1t, unsigned short* __restrict__ wr1t,
                              unsigned short* __restrict__ wl2t, unsigned short* __restrict__ wr2t,
                              unsigned short* __restrict__ wl3t, unsigned short* __restrict__ wr3t) {
    int b = blockIdx.x;
    int t = threadIdx.x;
    if (b < CNT_BLKS) {
        atomicAdd(&cnt[e_dst[b * 256 + t]], 1);
        return;
    }
    int idx = (b - CNT_BLKS) * 256 + t;
    const int S = HID * HID;  // 65536
    if (idx < 4 * S) {
        int sel = idx >> 16;
        int o = idx & (S - 1);
        const float* w = sel == 0 ? wl1 : sel == 1 ? wr1 : sel == 2 ? wl2 : wr2;
        unsigned short* wt = sel == 0 ? wl1t : sel == 1 ? wr1t : sel == 2 ? wl2t : wr2t;
        int n = o >> 8, k = o & 255;
        wt[o] = f2bf(w[k * HID + n]);
    } else {
        int r = idx - 4 * S;
        int sel = r >> 15;
        int o = r & 32767;
        const float* w = sel ? wr3 : wl3;
        unsigned short* wt = sel ? wr3t : wl3t;
        int n = o >> 8, k = o & 255;
        wt[o] = f2bf(w[k * EMB + n]);
    }
}

// ---------------- per-partition edge-count sums (8 blocks) ----------------
__global__ void k_psum(const int* __restrict__ cnt, int* __restrict__ psum) {
    __shared__ int sdata[256];
    int p = blockIdx.x;
    int lo = p * PART_SZ;
    int s = 0;
    for (int i = lo + threadIdx.x; i < lo + PART_SZ; i += 256) s += cnt[i];
    sdata[threadIdx.x] = s;
    __syncthreads();
    for (int off = 128; off > 0; off >>= 1) {
        if (threadIdx.x < off) sdata[threadIdx.x] += sdata[threadIdx.x + off];
        __syncthreads();
    }
    if (threadIdx.x == 0) psum[p] = sdata[0];
}

// ---------------- partitioned group-offset assignment via per-partition cursor --------
__global__ void k_assign(const int* __restrict__ cnt, const int* __restrict__ psum,
                         int* __restrict__ cursor, int* __restrict__ row_off,
                         int* __restrict__ fill_pos) {
    int n = blockIdx.x * 256 + threadIdx.x;
    if (n >= N_NODES) return;
    int p = n / PART_SZ;
    int base = 0;
    for (int i = 0; i < p; i++) base += psum[i];
    int deg = cnt[n];
    int beg = base + atomicAdd(&cursor[p], deg);
    row_off[n] = beg;
    fill_pos[n] = beg;
}

// ---------------- XCD-partitioned scatter: each block writes only its partition -------
// blockIdx&7 -> partition (= XCD via round-robin dispatch); output lines stay in ONE
// XCD L2 -> write-back once (fixes 16x write amplification of the naive scatter).
__global__ void k_scatter_part(const int* __restrict__ src, const int* __restrict__ dst,
                               int* __restrict__ fill_pos, int* __restrict__ sorted_src) {
    int part = blockIdx.x & 7;
    int lo = part * PART_SZ, hi = lo + PART_SZ;
    int idx = (blockIdx.x >> 3) * 256 + threadIdx.x;  // 0..65535
    for (int e = idx; e < N_EDGES; e += (SCAT_BLKS / 8) * 256) {
        int d = dst[e];
        if (d >= lo && d < hi) {
            int p = atomicAdd(&fill_pos[d], 1);
            sorted_src[p] = src[e];
        }
    }
}

// ---------------- input projection + fused BN stats (writes shard 0) ----------------
#define IP_BLOCKS 1024
__global__ __launch_bounds__(256) void k_input_proj(
        const float* __restrict__ x, const float* __restrict__ w,
        const float* __restrict__ bias, unsigned short* __restrict__ h,
        float* __restrict__ stats) {
    __shared__ float sbuf[2048];
    __shared__ float qbuf[2048];
    int t = threadIdx.x;
    int jg = t & 31;
    int ns = t >> 5;
    int j0 = jg * 8;

    float wreg[IN_F][8];
#pragma unroll
    for (int k = 0; k < IN_F; k++)
#pragma unroll
        for (int c = 0; c < 8; c++) wreg[k][c] = w[k * HID + j0 + c];
    float bj[8];
#pragma unroll
    for (int c = 0; c < 8; c++) bj[c] = bias[j0 + c];

    float s[8] = {}, q[8] = {};
    const int stride = IP_BLOCKS * 8;
    for (int base = blockIdx.x * 8 + ns; base < N_NODES; base += stride) {
        float xr[IN_F];
#pragma unroll
        for (int k = 0; k < IN_F; k++) xr[k] = x[base * IN_F + k];
        float acc[8];
#pragma unroll
        for (int c = 0; c < 8; c++) {
            float a = bj[c];
#pragma unroll
            for (int k = 0; k < IN_F; k++) a += xr[k] * wreg[k][c];
            acc[c] = a;
            s[c] += a;
            q[c] += a * a;
        }
        uint4 o;
        o.x = (unsigned)f2bf(acc[0]) | ((unsigned)f2bf(acc[1]) << 16);
        o.y = (unsigned)f2bf(acc[2]) | ((unsigned)f2bf(acc[3]) << 16);
        o.z = (unsigned)f2bf(acc[4]) | ((unsigned)f2bf(acc[5]) << 16);
        o.w = (unsigned)f2bf(acc[6]) | ((unsigned)f2bf(acc[7]) << 16);
        ((uint4*)h)[(size_t)base * 32 + jg] = o;
    }

#pragma unroll
    for (int c = 0; c < 8; c++) {
        sbuf[ns * 256 + j0 + c] = s[c];
        qbuf[ns * 256 + j0 + c] = q[c];
    }
    __syncthreads();
    float ss = 0.f, qq = 0.f;
#pragma unroll
    for (int n2 = 0; n2 < 8; n2++) {
        ss += sbuf[n2 * 256 + t];
        qq += qbuf[n2 * 256 + t];
    }
    atomicAdd(&stats[t], ss);
    atomicAdd(&stats[256 + t], qq);
}

// ---------------- BN apply + ReLU + optional fp8 shadow (reads 8 stats shards) --------
__global__ void k_bn_apply_relu(unsigned short* __restrict__ h, const float* __restrict__ stats,
                                const float* __restrict__ g, const float* __restrict__ b,
                                unsigned char* __restrict__ h8) {
    int idx = blockIdx.x * 256 + threadIdx.x;
    if (idx >= N_NODES * 32) return;
    int q = idx & 31;
    int j0 = q * 8;
    const float invn = 1.0f / (float)N_NODES;
    float sc[8], sh[8];
#pragma unroll
    for (int k = 0; k < 8; k++) {
        float ssum = 0.f, qsum = 0.f;
#pragma unroll
        for (int s = 0; s < NSHARD; s++) {
            ssum += stats[s * SSTRIDE + j0 + k];
            qsum += stats[s * SSTRIDE + 256 + j0 + k];
        }
        float mu = ssum * invn;
        float var = qsum * invn - mu * mu;
        float scale = g[j0 + k] * rsqrtf(var + BN_EPS);
        sc[k] = scale;
        sh[k] = b[j0 + k] - mu * scale;
    }
    uint4 v = ((uint4*)h)[idx];
    float f0 = fmaxf(bf_lo(v.x) * sc[0] + sh[0], 0.f);
    float f1 = fmaxf(bf_hi(v.x) * sc[1] + sh[1], 0.f);
    float f2 = fmaxf(bf_lo(v.y) * sc[2] + sh[2], 0.f);
    float f3 = fmaxf(bf_hi(v.y) * sc[3] + sh[3], 0.f);
    float f4 = fmaxf(bf_lo(v.z) * sc[4] + sh[4], 0.f);
    float f5 = fmaxf(bf_hi(v.z) * sc[5] + sh[5], 0.f);
    float f6 = fmaxf(bf_lo(v.w) * sc[6] + sh[6], 0.f);
    float f7 = fmaxf(bf_hi(v.w) * sc[7] + sh[7], 0.f);
    uint4 o;
    o.x = (unsigned)f2bf(f0) | ((unsigned)f2bf(f1) << 16);
    o.y = (unsigned)f2bf(f2) | ((unsigned)f2bf(f3) << 16);
    o.z = (unsigned)f2bf(f4) | ((unsigned)f2bf(f5) << 16);
    o.w = (unsigned)f2bf(f6) | ((unsigned)f2bf(f7) << 16);
    ((uint4*)h)[idx] = o;
    if (h8) {
        unsigned pa = __builtin_amdgcn_cvt_pk_fp8_f32(f0, f1, 0u, false);
        pa = __builtin_amdgcn_cvt_pk_fp8_f32(f2, f3, pa, true);
        unsigned pb = __builtin_amdgcn_cvt_pk_fp8_f32(f4, f5, 0u, false);
        pb = __builtin_amdgcn_cvt_pk_fp8_f32(f6, f7, pb, true);
        uint2 o8; o8.x = pa; o8.y = pb;
        ((uint2*)h8)[idx] = o8;
    }
}

// ---------------- fp8 neighbor mean aggregation: 16 lanes/node (degree from cnt) ------
__global__ void k_aggregate_fp8(const unsigned char* __restrict__ h8,
                                const int* __restrict__ row_off, const int* __restrict__ cnt,
                                const int* __restrict__ sorted_src,
                                unsigned short* __restrict__ agg) {
    int node = (blockIdx.x * blockDim.x + threadIdx.x) >> 4;
    int lane = threadIdx.x & 15;
    if (node >= N_NODES) return;
    int beg = row_off[node];
    int d = cnt[node];
    int end = beg + d;
    const uint4* h4 = (const uint4*)h8;
    float a[16] = {};
    for (int e = beg; e < end; e++) {
        int s = sorted_src[e];
        uint4 v = h4[(size_t)s * 16 + lane];
        floatx2 p;
        p = __builtin_amdgcn_cvt_pk_f32_fp8(v.x, false); a[0] += p.x;  a[1] += p.y;
        p = __builtin_amdgcn_cvt_pk_f32_fp8(v.x, true);  a[2] += p.x;  a[3] += p.y;
        p = __builtin_amdgcn_cvt_pk_f32_fp8(v.y, false); a[4] += p.x;  a[5] += p.y;
        p = __builtin_amdgcn_cvt_pk_f32_fp8(v.y, true);  a[6] += p.x;  a[7] += p.y;
        p = __builtin_amdgcn_cvt_pk_f32_fp8(v.z, false); a[8] += p.x;  a[9] += p.y;
        p = __builtin_amdgcn_cvt_pk_f32_fp8(v.z, true);  a[10] += p.x; a[11] += p.y;
        p = __builtin_amdgcn_cvt_pk_f32_fp8(v.w, false); a[12] += p.x; a[13] += p.y;
        p = __builtin_amdgcn_cvt_pk_f32_fp8(v.w, true);  a[14] += p.x; a[15] += p.y;
    }
    float inv = 1.0f / (float)(d > 1 ? d : 1);
    uint4 o0, o1;
    o0.x = (unsigned)f2bf(a[0] * inv)  | ((unsigned)f2bf(a[1] * inv) << 16);
    o0.y = (unsigned)f2bf(a[2] * inv)  | ((unsigned)f2bf(a[3] * inv) << 16);
    o0.z = (unsigned)f2bf(a[4] * inv)  | ((unsigned)f2bf(a[5] * inv) << 16);
    o0.w = (unsigned)f2bf(a[6] * inv)  | ((unsigned)f2bf(a[7] * inv) << 16);
    o1.x = (unsigned)f2bf(a[8] * inv)  | ((unsigned)f2bf(a[9] * inv) << 16);
    o1.y = (unsigned)f2bf(a[10] * inv) | ((unsigned)f2bf(a[11] * inv) << 16);
    o1.z = (unsigned)f2bf(a[12] * inv) | ((unsigned)f2bf(a[13] * inv) << 16);
    o1.w = (unsigned)f2bf(a[14] * inv) | ((unsigned)f2bf(a[15] * inv) << 16);
    ((uint4*)agg)[(size_t)node * 32 + lane * 2] = o0;
    ((uint4*)agg)[(size_t)node * 32 + lane * 2 + 1] = o1;
}

// ---------------- bf16 aggregate-mean ADD into fp32 out (layer-3, 128-wide) ----------
__global__ void k_aggregate_add(const unsigned short* __restrict__ G, const int* __restrict__ row_off,
                                const int* __restrict__ cnt, const int* __restrict__ sorted_src,
                                float* __restrict__ out) {
    int node = (blockIdx.x * blockDim.x + threadIdx.x) >> 4;
    int lane = threadIdx.x & 15;
    if (node >= N_NODES) return;
    int beg = row_off[node];
    int d = cnt[node];
    int end = beg + d;
    const uint4* h4 = (const uint4*)G;
    float a0 = 0.f, a1 = 0.f, a2 = 0.f, a3 = 0.f, a4 = 0.f, a5 = 0.f, a6 = 0.f, a7 = 0.f;
    for (int e = beg; e < end; e++) {
        int s = sorted_src[e];
        uint4 v = h4[(size_t)s * 16 + lane];
        a0 += bf_lo(v.x); a1 += bf_hi(v.x);
        a2 += bf_lo(v.y); a3 += bf_hi(v.y);
        a4 += bf_lo(v.z); a5 += bf_hi(v.z);
        a6 += bf_lo(v.w); a7 += bf_hi(v.w);
    }
    float inv = 1.0f / (float)(d > 1 ? d : 1);
    float4* ob = (float4*)(out + (size_t)node * EMB + lane * 8);
    float4 p0 = ob[0], p1 = ob[1];
    p0.x += a0 * inv; p0.y += a1 * inv; p0.z += a2 * inv; p0.w += a3 * inv;
    p1.x += a4 * inv; p1.y += a5 * inv; p1.z += a6 * inv; p1.w += a7 * inv;
    ob[0] = p0; ob[1] = p1;
}

#define BK 64
#define LPAD 72

// ---------------- dual-source bf16 MFMA GEMM + sharded stats (layers 1,2) ----------
template <int NCOL, bool STATS>
__global__ __launch_bounds__(512) void k_gemm_mfma(
        const unsigned short* __restrict__ A1, const unsigned short* __restrict__ B1t,
        const unsigned short* __restrict__ A2, const unsigned short* __restrict__ B2t,
        const float* __restrict__ bias, float* __restrict__ stats,
        unsigned short* __restrict__ Cout) {
    int b = blockIdx.x;
    int xcd = b & 7;
    int q = b >> 3;
    int cx = q & 1;
    int pr = (q >> 1) * 8 + xcd;
    int r0 = pr * 128;
    if (r0 >= N_NODES) return;
    int c0 = cx * 128;

    __shared__ unsigned short As[128 * LPAD];
    __shared__ unsigned short Bs[128 * LPAD];
    int t = threadIdx.x;
    int wave = t >> 6, lane = t & 63;
    int wm = wave >> 2, wn = wave & 3;
    int quad = lane >> 4, l15 = lane & 15;

    floatx4 acc[4][2];
#pragma unroll
    for (int i = 0; i < 4; i++)
#pragma unroll
        for (int j = 0; j < 2; j++) acc[i][j] = (floatx4){0.f, 0.f, 0.f, 0.f};

    int lrow = t >> 3;
    int lseg = t & 7;

#pragma unroll
    for (int s = 0; s < 2; s++) {
        const unsigned short* A = s ? A2 : A1;
        const unsigned short* B = s ? B2t : B1t;
        for (int k0 = 0; k0 < HID; k0 += BK) {
#pragma unroll
            for (int it = 0; it < 2; it++) {
                int row = lrow + it * 64;
                int r = r0 + row;
                uint4 va;
                if (r < N_NODES) va = *(const uint4*)&A[(size_t)r * HID + k0 + lseg * 8];
                else va = (uint4){0u, 0u, 0u, 0u};
                *(uint4*)&As[row * LPAD + lseg * 8] = va;
                uint4 vb = *(const uint4*)&B[(size_t)(c0 + row) * HID + k0 + lseg * 8];
                *(uint4*)&Bs[row * LPAD + lseg * 8] = vb;
            }
            __syncthreads();
#pragma unroll
            for (int kc = 0; kc < 2; kc++) {
                short8 a[4], bfr[2];
#pragma unroll
                for (int i = 0; i < 4; i++)
                    a[i] = *(const short8*)&As[(wm * 64 + i * 16 + l15) * LPAD + kc * 32 + quad * 8];
#pragma unroll
                for (int j = 0; j < 2; j++)
                    bfr[j] = *(const short8*)&Bs[(wn * 32 + j * 16 + l15) * LPAD + kc * 32 + quad * 8];
#pragma unroll
                for (int i = 0; i < 4; i++)
#pragma unroll
                    for (int j = 0; j < 2; j++)
                        acc[i][j] = __builtin_amdgcn_mfma_f32_16x16x32_bf16(a[i], bfr[j], acc[i][j], 0, 0, 0);
            }
            __syncthreads();
        }
    }

    float bv[2];
#pragma unroll
    for (int j = 0; j < 2; j++) bv[j] = bias[c0 + wn * 32 + j * 16 + l15];

    float s_part[2] = {0.f, 0.f};
    float q_part[2] = {0.f, 0.f};

#pragma unroll
    for (int i = 0; i < 4; i++) {
#pragma unroll
        for (int r = 0; r < 4; r++) {
            int m = r0 + wm * 64 + i * 16 + quad * 4 + r;
            if (m >= N_NODES) continue;
#pragma unroll
            for (int j = 0; j < 2; j++) {
                int n = c0 + wn * 32 + j * 16 + l15;
                float v = acc[i][j][r] + bv[j];
                if (STATS) { s_part[j] += v; q_part[j] += v * v; }
                Cout[(size_t)m * NCOL + n] = f2bf(v);
            }
        }
    }

    if (STATS) {
        float* sred = (float*)As;
        if (t < 256) sred[t] = 0.f;
        __syncthreads();
#pragma unroll
        for (int j = 0; j < 2; j++) {
            int cl = wn * 32 + j * 16 + l15;
            atomicAdd(&sred[cl], s_part[j]);
            atomicAdd(&sred[128 + cl], q_part[j]);
        }
        __syncthreads();
        if (t < 128) {
            int base = (pr & (NSHARD - 1)) * SSTRIDE;
            atomicAdd(&stats[base + c0 + t], sred[t]);
            atomicAdd(&stats[base + 256 + c0 + t], sred[128 + t]);
        }
    }
}

// ---------------- layer-3 dual-OUTPUT GEMM with BN+ReLU fused into A staging ----------
__global__ __launch_bounds__(512) void k_gemm_l3_dual(
        const unsigned short* __restrict__ A, const unsigned short* __restrict__ B1t,
        const unsigned short* __restrict__ B2t, const float* __restrict__ stats,
        const float* __restrict__ g, const float* __restrict__ be,
        const float* __restrict__ bl3, unsigned short* __restrict__ G,
        float* __restrict__ P) {
    __shared__ unsigned short As[128 * LPAD];
    __shared__ unsigned short B1s[128 * LPAD];
    __shared__ unsigned short B2s[128 * LPAD];
    __shared__ float scs[256], shs[256];
    int t = threadIdx.x;
    if (t < 256) {
        const float invn = 1.0f / (float)N_NODES;
        float ssum = 0.f, qsum = 0.f;
#pragma unroll
        for (int s = 0; s < NSHARD; s++) {
            ssum += stats[s * SSTRIDE + t];
            qsum += stats[s * SSTRIDE + 256 + t];
        }
        float mu = ssum * invn;
        float var = qsum * invn - mu * mu;
        float sc = g[t] * rsqrtf(var + BN_EPS);
        scs[t] = sc;
        shs[t] = be[t] - mu * sc;
    }
    __syncthreads();

    int wave = t >> 6, lane = t & 63;
    int wm = wave >> 2, wn = wave & 3;
    int quad = lane >> 4, l15 = lane & 15;
    int r0 = blockIdx.x * 128;
    int lrow = t >> 3;
    int lseg = t & 7;

    floatx4 acc1[4][2], acc2[4][2];
#pragma unroll
    for (int i = 0; i < 4; i++)
#pragma unroll
        for (int j = 0; j < 2; j++) {
            acc1[i][j] = (floatx4){0.f, 0.f, 0.f, 0.f};
            acc2[i][j] = (floatx4){0.f, 0.f, 0.f, 0.f};
        }

    for (int k0 = 0; k0 < HID; k0 += BK) {
        float sc8[8], sh8[8];
        int cb = k0 + lseg * 8;
#pragma unroll
        for (int c = 0; c < 8; c++) { sc8[c] = scs[cb + c]; sh8[c] = shs[cb + c]; }
#pragma unroll
        for (int it = 0; it < 2; it++) {
            int row = lrow + it * 64;
            int r = r0 + row;
            uint4 va;
            if (r < N_NODES) va = *(const uint4*)&A[(size_t)r * HID + cb];
            else va = (uint4){0u, 0u, 0u, 0u};
            float f0 = fmaxf(bf_lo(va.x) * sc8[0] + sh8[0], 0.f);
            float f1 = fmaxf(bf_hi(va.x) * sc8[1] + sh8[1], 0.f);
            float f2 = fmaxf(bf_lo(va.y) * sc8[2] + sh8[2], 0.f);
            float f3 = fmaxf(bf_hi(va.y) * sc8[3] + sh8[3], 0.f);
            float f4 = fmaxf(bf_lo(va.z) * sc8[4] + sh8[4], 0.f);
            float f5 = fmaxf(bf_hi(va.z) * sc8[5] + sh8[5], 0.f);
            float f6 = fmaxf(bf_lo(va.w) * sc8[6] + sh8[6], 0.f);
            float f7 = fmaxf(bf_hi(va.w) * sc8[7] + sh8[7], 0.f);
            if (r >= N_NODES) { f0=f1=f2=f3=f4=f5=f6=f7=0.f; }
            uint4 ov;
            ov.x = (unsigned)f2bf(f0) | ((unsigned)f2bf(f1) << 16);
            ov.y = (unsigned)f2bf(f2) | ((unsigned)f2bf(f3) << 16);
            ov.z = (unsigned)f2bf(f4) | ((unsigned)f2bf(f5) << 16);
            ov.w = (unsigned)f2bf(f6) | ((unsigned)f2bf(f7) << 16);
            *(uint4*)&As[row * LPAD + lseg * 8] = ov;
            *(uint4*)&B1s[row * LPAD + lseg * 8] = *(const uint4*)&B1t[(size_t)row * HID + cb];
            *(uint4*)&B2s[row * LPAD + lseg * 8] = *(const uint4*)&B2t[(size_t)row * HID + cb];
        }
        __syncthreads();
#pragma unroll
        for (int kc = 0; kc < 2; kc++) {
            short8 a[4], b1[2], b2[2];
#pragma unroll
            for (int i = 0; i < 4; i++)
                a[i] = *(const short8*)&As[(wm * 64 + i * 16 + l15) * LPAD + kc * 32 + quad * 8];
#pragma unroll
            for (int j = 0; j < 2; j++) {
                b1[j] = *(const short8*)&B1s[(wn * 32 + j * 16 + l15) * LPAD + kc * 32 + quad * 8];
                b2[j] = *(const short8*)&B2s[(wn * 32 + j * 16 + l15) * LPAD + kc * 32 + quad * 8];
            }
#pragma unroll
            for (int i = 0; i < 4; i++)
#pragma unroll
                for (int j = 0; j < 2; j++) {
                    acc1[i][j] = __builtin_amdgcn_mfma_f32_16x16x32_bf16(a[i], b1[j], acc1[i][j], 0, 0, 0);
                    acc2[i][j] = __builtin_amdgcn_mfma_f32_16x16x32_bf16(a[i], b2[j], acc2[i][j], 0, 0, 0);
                }
        }
        __syncthreads();
    }

    float bv[2];
#pragma unroll
    for (int j = 0; j < 2; j++) bv[j] = bl3[wn * 32 + j * 16 + l15];

#pragma unroll
    for (int i = 0; i < 4; i++) {
#pragma unroll
        for (int r = 0; r < 4; r++) {
            int m = r0 + wm * 64 + i * 16 + quad * 4 + r;
            if (m >= N_NODES) continue;
#pragma unroll
            for (int j = 0; j < 2; j++) {
                int n = wn * 32 + j * 16 + l15;
                G[(size_t)m * EMB + n] = f2bf(acc1[i][j][r]);
                P[(size_t)m * EMB + n] = acc2[i][j][r] + bv[j];
            }
        }
    }
}

extern "C" void kernel_launch(void* const* d_in, const int* in_sizes, int n_in,
                              void* d_out, int out_size, void* d_ws, size_t ws_size,
                              hipStream_t stream) {
    const float* x    = (const float*)d_in[0];
    const int*   ei   = (const int*)d_in[1];
    const float* w_in = (const float*)d_in[2];
    const float* b_in = (const float*)d_in[3];
    const float* g_in = (const float*)d_in[4];
    const float* be_in= (const float*)d_in[5];
    const float* wl1  = (const float*)d_in[6];
    const float* bl1  = (const float*)d_in[7];
    const float* wr1  = (const float*)d_in[8];
    const float* g1   = (const float*)d_in[9];
    const float* be1  = (const float*)d_in[10];
    const float* wl2  = (const float*)d_in[11];
    const float* bl2  = (const float*)d_in[12];
    const float* wr2  = (const float*)d_in[13];
    const float* g2   = (const float*)d_in[14];
    const float* be2  = (const float*)d_in[15];
    const float* wl3  = (const float*)d_in[16];
    const float* bl3  = (const float*)d_in[17];
    const float* wr3  = (const float*)d_in[18];
    float* out = (float*)d_out;

    char* p = (char*)d_ws;
    auto alloc = [&](size_t bytes) -> void* {
        void* r = (void*)p;
        p += (bytes + 255) & ~(size_t)255;
        return r;
    };
    // zero-region: cnt + cursor + 3 sharded stats buffers (contiguous)
    int*   cnt    = (int*)alloc((size_t)N_NODES * 4);
    int*   cursor = (int*)alloc(256);   // 8 per-partition cursors (+pad)
    float* stats0 = (float*)alloc((size_t)NSHARD * SSTRIDE * 4);
    float* stats1 = (float*)alloc((size_t)NSHARD * SSTRIDE * 4);
    float* stats2 = (float*)alloc((size_t)NSHARD * SSTRIDE * 4);
    size_t zlen = (size_t)((char*)stats2 + NSHARD * SSTRIDE * 4 - (char*)cnt);

    unsigned short* bufA = (unsigned short*)alloc((size_t)N_NODES * HID * 2);
    unsigned short* bufB = (unsigned short*)alloc((size_t)N_NODES * HID * 2);
    unsigned short* bufC = (unsigned short*)alloc((size_t)N_NODES * HID * 2);
    unsigned char*  h8   = (unsigned char*)alloc((size_t)N_NODES * HID);
    unsigned short* wl1t = (unsigned short*)alloc((size_t)HID * HID * 2);
    unsigned short* wr1t = (unsigned short*)alloc((size_t)HID * HID * 2);
    unsigned short* wl2t = (unsigned short*)alloc((size_t)HID * HID * 2);
    unsigned short* wr2t = (unsigned short*)alloc((size_t)HID * HID * 2);
    unsigned short* wl3t = (unsigned short*)alloc((size_t)EMB * HID * 2);
    unsigned short* wr3t = (unsigned short*)alloc((size_t)EMB * HID * 2);
    int*   row_off    = (int*)alloc((size_t)(N_NODES + 1) * 4);
    int*   fill_pos   = (int*)alloc((size_t)N_NODES * 4);
    int*   sorted_src = (int*)alloc((size_t)N_EDGES * 4);
    int*   psum       = (int*)alloc(256);

    const int* e_src = ei;
    const int* e_dst = ei + N_EDGES;

    hipMemsetAsync(cnt, 0, zlen, stream);
    k_count_wconv<<<CNT_BLKS + WCONV_BLKS, 256, 0, stream>>>(
        e_dst, cnt, wl1, wr1, wl2, wr2, wl3, wr3, wl1t, wr1t, wl2t, wr2t, wl3t, wr3t);
    k_psum<<<NPART, 256, 0, stream>>>(cnt, psum);
    k_assign<<<N_SCAN_BLKS, 256, 0, stream>>>(cnt, psum, cursor, row_off, fill_pos);
    k_scatter_part<<<SCAT_BLKS, 256, 0, stream>>>(e_src, e_dst, fill_pos, sorted_src);

    k_input_proj<<<IP_BLOCKS, 256, 0, stream>>>(x, w_in, b_in, bufA, stats0);
    k_bn_apply_relu<<<(N_NODES * 32 + 255) / 256, 256, 0, stream>>>(bufA, stats0, g_in, be_in, h8);

    const int GEMM_BLKS = 784;
    int aggF8_blocks = (N_NODES * 16 + 255) / 256;

    // SAGE layer 1
    k_aggregate_fp8<<<aggF8_blocks, 256, 0, stream>>>(h8, row_off, cnt, sorted_src, bufC);
    k_gemm_mfma<HID, true><<<GEMM_BLKS, 512, 0, stream>>>(bufC, wl1t, bufA, wr1t, bl1, stats1, bufB);
    k_bn_apply_relu<<<(N_NODES * 32 + 255) / 256, 256, 0, stream>>>(bufB, stats1, g1, be1, h8);

    // SAGE layer 2 (raw h2 + stats2; BN deferred into layer-3 GEMM)
    k_aggregate_fp8<<<aggF8_blocks, 256, 0, stream>>>(h8, row_off, cnt, sorted_src, bufC);
    k_gemm_mfma<HID, true><<<GEMM_BLKS, 512, 0, stream>>>(bufC, wl2t, bufB, wr2t, bl2, stats2, bufA);

    // layer-3 dual GEMM with fused BN, then out += neighbor-mean of G
    k_gemm_l3_dual<<<(N_NODES + 127) / 128, 512, 0, stream>>>(
        bufA, wl3t, wr3t, stats2, g2, be2, bl3, bufB, out);
    k_aggregate_add<<<(N_NODES * 16 + 255) / 256, 256, 0, stream>>>(bufB, row_off, cnt, sorted_src, out);
}

// Round 12
// 508.550 us; speedup vs baseline: 2.1303x; 2.1303x over previous
//
#include <hip/hip_runtime.h>

#define N_NODES 50000
#define N_EDGES 800000
#define IN_F 10
#define HID 256
#define EMB 128
#define BN_EPS 1e-5f
#define N_SCAN_BLKS ((N_NODES + 255) / 256)  // 196
#define CNT_BLKS (N_EDGES / 256)             // 3125
#define WCONV_ELEMS (4 * HID * HID + 2 * EMB * HID)  // 327680
#define WCONV_BLKS (WCONV_ELEMS / 256)       // 1280
#define SSTRIDE 512
#define NSHARD 8
#define NPART 8
#define PART_SZ (N_NODES / NPART)            // 6250
#define SCAT_BLKS 2048

typedef __attribute__((ext_vector_type(8))) short short8;
typedef __attribute__((ext_vector_type(4))) float floatx4;
typedef __attribute__((ext_vector_type(2))) float floatx2;

__device__ __forceinline__ unsigned short f2bf(float f) {
    unsigned u = __float_as_uint(f);
    unsigned r = (u + 0x7fffu + ((u >> 16) & 1u)) >> 16;
    return (unsigned short)r;
}
__device__ __forceinline__ float bf_lo(unsigned int u) { return __uint_as_float(u << 16); }
__device__ __forceinline__ float bf_hi(unsigned int u) { return __uint_as_float(u & 0xffff0000u); }
__device__ __forceinline__ float bf2f(unsigned short s) { return __uint_as_float(((unsigned)s) << 16); }

// ---------------- fused: degree count + all 6 weight convert/transpose ----------------
__global__ void k_count_wconv(const int* __restrict__ e_dst, int* __restrict__ cnt,
                              const float* __restrict__ wl1, const float* __restrict__ wr1,
                              const float* __restrict__ wl2, const float* __restrict__ wr2,
                              const float* __restrict__ wl3, const float* __restrict__ wr3,
                              unsigned short* __restrict__ wl1t, unsigned short* __restrict__ wr1t,
                              unsigned short* __restrict__ wl2t, unsigned short* __restrict__ wr2t,
                              unsigned short* __restrict__ wl3t, unsigned short* __restrict__ wr3t) {
    int b = blockIdx.x;
    int t = threadIdx.x;
    if (b < CNT_BLKS) {
        atomicAdd(&cnt[e_dst[b * 256 + t]], 1);
        return;
    }
    int idx = (b - CNT_BLKS) * 256 + t;
    const int S = HID * HID;  // 65536
    if (idx < 4 * S) {
        int sel = idx >> 16;
        int o = idx & (S - 1);
        const float* w = sel == 0 ? wl1 : sel == 1 ? wr1 : sel == 2 ? wl2 : wr2;
        unsigned short* wt = sel == 0 ? wl1t : sel == 1 ? wr1t : sel == 2 ? wl2t : wr2t;
        int n = o >> 8, k = o & 255;
        wt[o] = f2bf(w[k * HID + n]);
    } else {
        int r = idx - 4 * S;
        int sel = r >> 15;
        int o = r & 32767;
        const float* w = sel ? wr3 : wl3;
        unsigned short* wt = sel ? wr3t : wl3t;
        int n = o >> 8, k = o & 255;
        wt[o] = f2bf(w[k * EMB + n]);
    }
}

// ---------------- 3-phase exclusive scan of cnt -> row_off / fill_pos ----------------
// Global scan over contiguous node ranges => partition p's edge slice
// [row_off[p*PART_SZ], row_off[(p+1)*PART_SZ]) is automatically contiguous.
__global__ void k_reduce_cnt(const int* __restrict__ cnt, int* __restrict__ part) {
    __shared__ int sdata[256];
    int i = blockIdx.x * 256 + threadIdx.x;
    sdata[threadIdx.x] = (i < N_NODES) ? cnt[i] : 0;
    __syncthreads();
    for (int off = 128; off > 0; off >>= 1) {
        if (threadIdx.x < off) sdata[threadIdx.x] += sdata[threadIdx.x + off];
        __syncthreads();
    }
    if (threadIdx.x == 0) part[blockIdx.x] = sdata[0];
}

__global__ void k_scan_part(const int* __restrict__ part, int* __restrict__ partoff,
                            int* __restrict__ row_off_last) {
    __shared__ int buf[256];
    int tid = threadIdx.x;
    int v = (tid < N_SCAN_BLKS) ? part[tid] : 0;
    buf[tid] = v;
    __syncthreads();
    for (int off = 1; off < 256; off <<= 1) {
        int t = (tid >= off) ? buf[tid - off] : 0;
        __syncthreads();
        buf[tid] += t;
        __syncthreads();
    }
    if (tid < N_SCAN_BLKS) partoff[tid] = buf[tid] - v;
    if (tid == 255) *row_off_last = buf[255];
}

__global__ void k_scan_final(const int* __restrict__ cnt, const int* __restrict__ partoff,
                             int* __restrict__ row_off, int* __restrict__ fill_pos) {
    __shared__ int buf[256];
    int tid = threadIdx.x;
    int i = blockIdx.x * 256 + tid;
    int v = (i < N_NODES) ? cnt[i] : 0;
    buf[tid] = v;
    __syncthreads();
    for (int off = 1; off < 256; off <<= 1) {
        int t = (tid >= off) ? buf[tid - off] : 0;
        __syncthreads();
        buf[tid] += t;
        __syncthreads();
    }
    if (i < N_NODES) {
        int excl = partoff[blockIdx.x] + buf[tid] - v;
        row_off[i] = excl;
        fill_pos[i] = excl;
    }
}

// ---------------- XCD-partitioned scatter: each block writes only its partition -------
// blockIdx&7 -> partition (= XCD via round-robin dispatch); output lines stay in ONE
// XCD L2 -> write-back once (fixes 16x write amplification of the naive scatter).
__global__ void k_scatter_part(const int* __restrict__ src, const int* __restrict__ dst,
                               int* __restrict__ fill_pos, int* __restrict__ sorted_src) {
    int part = blockIdx.x & 7;
    int lo = part * PART_SZ, hi = lo + PART_SZ;
    int idx = (blockIdx.x >> 3) * 256 + threadIdx.x;  // 0..65535
    for (int e = idx; e < N_EDGES; e += (SCAT_BLKS / 8) * 256) {
        int d = dst[e];
        if (d >= lo && d < hi) {
            int p = atomicAdd(&fill_pos[d], 1);
            sorted_src[p] = src[e];
        }
    }
}

// ---------------- input projection + fused BN stats (writes shard 0) ----------------
#define IP_BLOCKS 1024
__global__ __launch_bounds__(256) void k_input_proj(
        const float* __restrict__ x, const float* __restrict__ w,
        const float* __restrict__ bias, unsigned short* __restrict__ h,
        float* __restrict__ stats) {
    __shared__ float sbuf[2048];
    __shared__ float qbuf[2048];
    int t = threadIdx.x;
    int jg = t & 31;
    int ns = t >> 5;
    int j0 = jg * 8;

    float wreg[IN_F][8];
#pragma unroll
    for (int k = 0; k < IN_F; k++)
#pragma unroll
        for (int c = 0; c < 8; c++) wreg[k][c] = w[k * HID + j0 + c];
    float bj[8];
#pragma unroll
    for (int c = 0; c < 8; c++) bj[c] = bias[j0 + c];

    float s[8] = {}, q[8] = {};
    const int stride = IP_BLOCKS * 8;
    for (int base = blockIdx.x * 8 + ns; base < N_NODES; base += stride) {
        float xr[IN_F];
#pragma unroll
        for (int k = 0; k < IN_F; k++) xr[k] = x[base * IN_F + k];
        float acc[8];
#pragma unroll
        for (int c = 0; c < 8; c++) {
            float a = bj[c];
#pragma unroll
            for (int k = 0; k < IN_F; k++) a += xr[k] * wreg[k][c];
            acc[c] = a;
            s[c] += a;
            q[c] += a * a;
        }
        uint4 o;
        o.x = (unsigned)f2bf(acc[0]) | ((unsigned)f2bf(acc[1]) << 16);
        o.y = (unsigned)f2bf(acc[2]) | ((unsigned)f2bf(acc[3]) << 16);
        o.z = (unsigned)f2bf(acc[4]) | ((unsigned)f2bf(acc[5]) << 16);
        o.w = (unsigned)f2bf(acc[6]) | ((unsigned)f2bf(acc[7]) << 16);
        ((uint4*)h)[(size_t)base * 32 + jg] = o;
    }

#pragma unroll
    for (int c = 0; c < 8; c++) {
        sbuf[ns * 256 + j0 + c] = s[c];
        qbuf[ns * 256 + j0 + c] = q[c];
    }
    __syncthreads();
    float ss = 0.f, qq = 0.f;
#pragma unroll
    for (int n2 = 0; n2 < 8; n2++) {
        ss += sbuf[n2 * 256 + t];
        qq += qbuf[n2 * 256 + t];
    }
    atomicAdd(&stats[t], ss);
    atomicAdd(&stats[256 + t], qq);
}

// ---------------- BN apply + ReLU + optional fp8 shadow (reads 8 stats shards) --------
__global__ void k_bn_apply_relu(unsigned short* __restrict__ h, const float* __restrict__ stats,
                                const float* __restrict__ g, const float* __restrict__ b,
                                unsigned char* __restrict__ h8) {
    int idx = blockIdx.x * 256 + threadIdx.x;
    if (idx >= N_NODES * 32) return;
    int q = idx & 31;
    int j0 = q * 8;
    const float invn = 1.0f / (float)N_NODES;
    float sc[8], sh[8];
#pragma unroll
    for (int k = 0; k < 8; k++) {
        float ssum = 0.f, qsum = 0.f;
#pragma unroll
        for (int s = 0; s < NSHARD; s++) {
            ssum += stats[s * SSTRIDE + j0 + k];
            qsum += stats[s * SSTRIDE + 256 + j0 + k];
        }
        float mu = ssum * invn;
        float var = qsum * invn - mu * mu;
        float scale = g[j0 + k] * rsqrtf(var + BN_EPS);
        sc[k] = scale;
        sh[k] = b[j0 + k] - mu * scale;
    }
    uint4 v = ((uint4*)h)[idx];
    float f0 = fmaxf(bf_lo(v.x) * sc[0] + sh[0], 0.f);
    float f1 = fmaxf(bf_hi(v.x) * sc[1] + sh[1], 0.f);
    float f2 = fmaxf(bf_lo(v.y) * sc[2] + sh[2], 0.f);
    float f3 = fmaxf(bf_hi(v.y) * sc[3] + sh[3], 0.f);
    float f4 = fmaxf(bf_lo(v.z) * sc[4] + sh[4], 0.f);
    float f5 = fmaxf(bf_hi(v.z) * sc[5] + sh[5], 0.f);
    float f6 = fmaxf(bf_lo(v.w) * sc[6] + sh[6], 0.f);
    float f7 = fmaxf(bf_hi(v.w) * sc[7] + sh[7], 0.f);
    uint4 o;
    o.x = (unsigned)f2bf(f0) | ((unsigned)f2bf(f1) << 16);
    o.y = (unsigned)f2bf(f2) | ((unsigned)f2bf(f3) << 16);
    o.z = (unsigned)f2bf(f4) | ((unsigned)f2bf(f5) << 16);
    o.w = (unsigned)f2bf(f6) | ((unsigned)f2bf(f7) << 16);
    ((uint4*)h)[idx] = o;
    if (h8) {
        unsigned pa = __builtin_amdgcn_cvt_pk_fp8_f32(f0, f1, 0u, false);
        pa = __builtin_amdgcn_cvt_pk_fp8_f32(f2, f3, pa, true);
        unsigned pb = __builtin_amdgcn_cvt_pk_fp8_f32(f4, f5, 0u, false);
        pb = __builtin_amdgcn_cvt_pk_fp8_f32(f6, f7, pb, true);
        uint2 o8; o8.x = pa; o8.y = pb;
        ((uint2*)h8)[idx] = o8;
    }
}

// ---------------- fp8 neighbor mean aggregation: 16 lanes/node (degree from cnt) ------
__global__ void k_aggregate_fp8(const unsigned char* __restrict__ h8,
                                const int* __restrict__ row_off, const int* __restrict__ cnt,
                                const int* __restrict__ sorted_src,
                                unsigned short* __restrict__ agg) {
    int node = (blockIdx.x * blockDim.x + threadIdx.x) >> 4;
    int lane = threadIdx.x & 15;
    if (node >= N_NODES) return;
    int beg = row_off[node];
    int d = cnt[node];
    int end = beg + d;
    const uint4* h4 = (const uint4*)h8;
    float a[16] = {};
    for (int e = beg; e < end; e++) {
        int s = sorted_src[e];
        uint4 v = h4[(size_t)s * 16 + lane];
        floatx2 p;
        p = __builtin_amdgcn_cvt_pk_f32_fp8(v.x, false); a[0] += p.x;  a[1] += p.y;
        p = __builtin_amdgcn_cvt_pk_f32_fp8(v.x, true);  a[2] += p.x;  a[3] += p.y;
        p = __builtin_amdgcn_cvt_pk_f32_fp8(v.y, false); a[4] += p.x;  a[5] += p.y;
        p = __builtin_amdgcn_cvt_pk_f32_fp8(v.y, true);  a[6] += p.x;  a[7] += p.y;
        p = __builtin_amdgcn_cvt_pk_f32_fp8(v.z, false); a[8] += p.x;  a[9] += p.y;
        p = __builtin_amdgcn_cvt_pk_f32_fp8(v.z, true);  a[10] += p.x; a[11] += p.y;
        p = __builtin_amdgcn_cvt_pk_f32_fp8(v.w, false); a[12] += p.x; a[13] += p.y;
        p = __builtin_amdgcn_cvt_pk_f32_fp8(v.w, true);  a[14] += p.x; a[15] += p.y;
    }
    float inv = 1.0f / (float)(d > 1 ? d : 1);
    uint4 o0, o1;
    o0.x = (unsigned)f2bf(a[0] * inv)  | ((unsigned)f2bf(a[1] * inv) << 16);
    o0.y = (unsigned)f2bf(a[2] * inv)  | ((unsigned)f2bf(a[3] * inv) << 16);
    o0.z = (unsigned)f2bf(a[4] * inv)  | ((unsigned)f2bf(a[5] * inv) << 16);
    o0.w = (unsigned)f2bf(a[6] * inv)  | ((unsigned)f2bf(a[7] * inv) << 16);
    o1.x = (unsigned)f2bf(a[8] * inv)  | ((unsigned)f2bf(a[9] * inv) << 16);
    o1.y = (unsigned)f2bf(a[10] * inv) | ((unsigned)f2bf(a[11] * inv) << 16);
    o1.z = (unsigned)f2bf(a[12] * inv) | ((unsigned)f2bf(a[13] * inv) << 16);
    o1.w = (unsigned)f2bf(a[14] * inv) | ((unsigned)f2bf(a[15] * inv) << 16);
    ((uint4*)agg)[(size_t)node * 32 + lane * 2] = o0;
    ((uint4*)agg)[(size_t)node * 32 + lane * 2 + 1] = o1;
}

// ---------------- bf16 aggregate-mean ADD into fp32 out (layer-3, 128-wide) ----------
__global__ void k_aggregate_add(const unsigned short* __restrict__ G, const int* __restrict__ row_off,
                                const int* __restrict__ cnt, const int* __restrict__ sorted_src,
                                float* __restrict__ out) {
    int node = (blockIdx.x * blockDim.x + threadIdx.x) >> 4;
    int lane = threadIdx.x & 15;
    if (node >= N_NODES) return;
    int beg = row_off[node];
    int d = cnt[node];
    int end = beg + d;
    const uint4* h4 = (const uint4*)G;
    float a0 = 0.f, a1 = 0.f, a2 = 0.f, a3 = 0.f, a4 = 0.f, a5 = 0.f, a6 = 0.f, a7 = 0.f;
    for (int e = beg; e < end; e++) {
        int s = sorted_src[e];
        uint4 v = h4[(size_t)s * 16 + lane];
        a0 += bf_lo(v.x); a1 += bf_hi(v.x);
        a2 += bf_lo(v.y); a3 += bf_hi(v.y);
        a4 += bf_lo(v.z); a5 += bf_hi(v.z);
        a6 += bf_lo(v.w); a7 += bf_hi(v.w);
    }
    float inv = 1.0f / (float)(d > 1 ? d : 1);
    float4* ob = (float4*)(out + (size_t)node * EMB + lane * 8);
    float4 p0 = ob[0], p1 = ob[1];
    p0.x += a0 * inv; p0.y += a1 * inv; p0.z += a2 * inv; p0.w += a3 * inv;
    p1.x += a4 * inv; p1.y += a5 * inv; p1.z += a6 * inv; p1.w += a7 * inv;
    ob[0] = p0; ob[1] = p1;
}

#define BK 64
#define LPAD 72

// ---------------- dual-source bf16 MFMA GEMM + sharded stats (layers 1,2) ----------
template <int NCOL, bool STATS>
__global__ __launch_bounds__(512) void k_gemm_mfma(
        const unsigned short* __restrict__ A1, const unsigned short* __restrict__ B1t,
        const unsigned short* __restrict__ A2, const unsigned short* __restrict__ B2t,
        const float* __restrict__ bias, float* __restrict__ stats,
        unsigned short* __restrict__ Cout) {
    int b = blockIdx.x;
    int xcd = b & 7;
    int q = b >> 3;
    int cx = q & 1;
    int pr = (q >> 1) * 8 + xcd;
    int r0 = pr * 128;
    if (r0 >= N_NODES) return;
    int c0 = cx * 128;

    __shared__ unsigned short As[128 * LPAD];
    __shared__ unsigned short Bs[128 * LPAD];
    int t = threadIdx.x;
    int wave = t >> 6, lane = t & 63;
    int wm = wave >> 2, wn = wave & 3;
    int quad = lane >> 4, l15 = lane & 15;

    floatx4 acc[4][2];
#pragma unroll
    for (int i = 0; i < 4; i++)
#pragma unroll
        for (int j = 0; j < 2; j++) acc[i][j] = (floatx4){0.f, 0.f, 0.f, 0.f};

    int lrow = t >> 3;
    int lseg = t & 7;

#pragma unroll
    for (int s = 0; s < 2; s++) {
        const unsigned short* A = s ? A2 : A1;
        const unsigned short* B = s ? B2t : B1t;
        for (int k0 = 0; k0 < HID; k0 += BK) {
#pragma unroll
            for (int it = 0; it < 2; it++) {
                int row = lrow + it * 64;
                int r = r0 + row;
                uint4 va;
                if (r < N_NODES) va = *(const uint4*)&A[(size_t)r * HID + k0 + lseg * 8];
                else va = (uint4){0u, 0u, 0u, 0u};
                *(uint4*)&As[row * LPAD + lseg * 8] = va;
                uint4 vb = *(const uint4*)&B[(size_t)(c0 + row) * HID + k0 + lseg * 8];
                *(uint4*)&Bs[row * LPAD + lseg * 8] = vb;
            }
            __syncthreads();
#pragma unroll
            for (int kc = 0; kc < 2; kc++) {
                short8 a[4], bfr[2];
#pragma unroll
                for (int i = 0; i < 4; i++)
                    a[i] = *(const short8*)&As[(wm * 64 + i * 16 + l15) * LPAD + kc * 32 + quad * 8];
#pragma unroll
                for (int j = 0; j < 2; j++)
                    bfr[j] = *(const short8*)&Bs[(wn * 32 + j * 16 + l15) * LPAD + kc * 32 + quad * 8];
#pragma unroll
                for (int i = 0; i < 4; i++)
#pragma unroll
                    for (int j = 0; j < 2; j++)
                        acc[i][j] = __builtin_amdgcn_mfma_f32_16x16x32_bf16(a[i], bfr[j], acc[i][j], 0, 0, 0);
            }
            __syncthreads();
        }
    }

    float bv[2];
#pragma unroll
    for (int j = 0; j < 2; j++) bv[j] = bias[c0 + wn * 32 + j * 16 + l15];

    float s_part[2] = {0.f, 0.f};
    float q_part[2] = {0.f, 0.f};

#pragma unroll
    for (int i = 0; i < 4; i++) {
#pragma unroll
        for (int r = 0; r < 4; r++) {
            int m = r0 + wm * 64 + i * 16 + quad * 4 + r;
            if (m >= N_NODES) continue;
#pragma unroll
            for (int j = 0; j < 2; j++) {
                int n = c0 + wn * 32 + j * 16 + l15;
                float v = acc[i][j][r] + bv[j];
                if (STATS) { s_part[j] += v; q_part[j] += v * v; }
                Cout[(size_t)m * NCOL + n] = f2bf(v);
            }
        }
    }

    if (STATS) {
        float* sred = (float*)As;
        if (t < 256) sred[t] = 0.f;
        __syncthreads();
#pragma unroll
        for (int j = 0; j < 2; j++) {
            int cl = wn * 32 + j * 16 + l15;
            atomicAdd(&sred[cl], s_part[j]);
            atomicAdd(&sred[128 + cl], q_part[j]);
        }
        __syncthreads();
        if (t < 128) {
            int base = (pr & (NSHARD - 1)) * SSTRIDE;
            atomicAdd(&stats[base + c0 + t], sred[t]);
            atomicAdd(&stats[base + 256 + c0 + t], sred[128 + t]);
        }
    }
}

// ---------------- layer-3 dual-OUTPUT GEMM with BN+ReLU fused into A staging ----------
__global__ __launch_bounds__(512) void k_gemm_l3_dual(
        const unsigned short* __restrict__ A, const unsigned short* __restrict__ B1t,
        const unsigned short* __restrict__ B2t, const float* __restrict__ stats,
        const float* __restrict__ g, const float* __restrict__ be,
        const float* __restrict__ bl3, unsigned short* __restrict__ G,
        float* __restrict__ P) {
    __shared__ unsigned short As[128 * LPAD];
    __shared__ unsigned short B1s[128 * LPAD];
    __shared__ unsigned short B2s[128 * LPAD];
    __shared__ float scs[256], shs[256];
    int t = threadIdx.x;
    if (t < 256) {
        const float invn = 1.0f / (float)N_NODES;
        float ssum = 0.f, qsum = 0.f;
#pragma unroll
        for (int s = 0; s < NSHARD; s++) {
            ssum += stats[s * SSTRIDE + t];
            qsum += stats[s * SSTRIDE + 256 + t];
        }
        float mu = ssum * invn;
        float var = qsum * invn - mu * mu;
        float sc = g[t] * rsqrtf(var + BN_EPS);
        scs[t] = sc;
        shs[t] = be[t] - mu * sc;
    }
    __syncthreads();

    int wave = t >> 6, lane = t & 63;
    int wm = wave >> 2, wn = wave & 3;
    int quad = lane >> 4, l15 = lane & 15;
    int r0 = blockIdx.x * 128;
    int lrow = t >> 3;
    int lseg = t & 7;

    floatx4 acc1[4][2], acc2[4][2];
#pragma unroll
    for (int i = 0; i < 4; i++)
#pragma unroll
        for (int j = 0; j < 2; j++) {
            acc1[i][j] = (floatx4){0.f, 0.f, 0.f, 0.f};
            acc2[i][j] = (floatx4){0.f, 0.f, 0.f, 0.f};
        }

    for (int k0 = 0; k0 < HID; k0 += BK) {
        float sc8[8], sh8[8];
        int cb = k0 + lseg * 8;
#pragma unroll
        for (int c = 0; c < 8; c++) { sc8[c] = scs[cb + c]; sh8[c] = shs[cb + c]; }
#pragma unroll
        for (int it = 0; it < 2; it++) {
            int row = lrow + it * 64;
            int r = r0 + row;
            uint4 va;
            if (r < N_NODES) va = *(const uint4*)&A[(size_t)r * HID + cb];
            else va = (uint4){0u, 0u, 0u, 0u};
            float f0 = fmaxf(bf_lo(va.x) * sc8[0] + sh8[0], 0.f);
            float f1 = fmaxf(bf_hi(va.x) * sc8[1] + sh8[1], 0.f);
            float f2 = fmaxf(bf_lo(va.y) * sc8[2] + sh8[2], 0.f);
            float f3 = fmaxf(bf_hi(va.y) * sc8[3] + sh8[3], 0.f);
            float f4 = fmaxf(bf_lo(va.z) * sc8[4] + sh8[4], 0.f);
            float f5 = fmaxf(bf_hi(va.z) * sc8[5] + sh8[5], 0.f);
            float f6 = fmaxf(bf_lo(va.w) * sc8[6] + sh8[6], 0.f);
            float f7 = fmaxf(bf_hi(va.w) * sc8[7] + sh8[7], 0.f);
            if (r >= N_NODES) { f0=f1=f2=f3=f4=f5=f6=f7=0.f; }
            uint4 ov;
            ov.x = (unsigned)f2bf(f0) | ((unsigned)f2bf(f1) << 16);
            ov.y = (unsigned)f2bf(f2) | ((unsigned)f2bf(f3) << 16);
            ov.z = (unsigned)f2bf(f4) | ((unsigned)f2bf(f5) << 16);
            ov.w = (unsigned)f2bf(f6) | ((unsigned)f2bf(f7) << 16);
            *(uint4*)&As[row * LPAD + lseg * 8] = ov;
            *(uint4*)&B1s[row * LPAD + lseg * 8] = *(const uint4*)&B1t[(size_t)row * HID + cb];
            *(uint4*)&B2s[row * LPAD + lseg * 8] = *(const uint4*)&B2t[(size_t)row * HID + cb];
        }
        __syncthreads();
#pragma unroll
        for (int kc = 0; kc < 2; kc++) {
            short8 a[4], b1[2], b2[2];
#pragma unroll
            for (int i = 0; i < 4; i++)
                a[i] = *(const short8*)&As[(wm * 64 + i * 16 + l15) * LPAD + kc * 32 + quad * 8];
#pragma unroll
            for (int j = 0; j < 2; j++) {
                b1[j] = *(const short8*)&B1s[(wn * 32 + j * 16 + l15) * LPAD + kc * 32 + quad * 8];
                b2[j] = *(const short8*)&B2s[(wn * 32 + j * 16 + l15) * LPAD + kc * 32 + quad * 8];
            }
#pragma unroll
            for (int i = 0; i < 4; i++)
#pragma unroll
                for (int j = 0; j < 2; j++) {
                    acc1[i][j] = __builtin_amdgcn_mfma_f32_16x16x32_bf16(a[i], b1[j], acc1[i][j], 0, 0, 0);
                    acc2[i][j] = __builtin_amdgcn_mfma_f32_16x16x32_bf16(a[i], b2[j], acc2[i][j], 0, 0, 0);
                }
        }
        __syncthreads();
    }

    float bv[2];
#pragma unroll
    for (int j = 0; j < 2; j++) bv[j] = bl3[wn * 32 + j * 16 + l15];

#pragma unroll
    for (int i = 0; i < 4; i++) {
#pragma unroll
        for (int r = 0; r < 4; r++) {
            int m = r0 + wm * 64 + i * 16 + quad * 4 + r;
            if (m >= N_NODES) continue;
#pragma unroll
            for (int j = 0; j < 2; j++) {
                int n = wn * 32 + j * 16 + l15;
                G[(size_t)m * EMB + n] = f2bf(acc1[i][j][r]);
                P[(size_t)m * EMB + n] = acc2[i][j][r] + bv[j];
            }
        }
    }
}

extern "C" void kernel_launch(void* const* d_in, const int* in_sizes, int n_in,
                              void* d_out, int out_size, void* d_ws, size_t ws_size,
                              hipStream_t stream) {
    const float* x    = (const float*)d_in[0];
    const int*   ei   = (const int*)d_in[1];
    const float* w_in = (const float*)d_in[2];
    const float* b_in = (const float*)d_in[3];
    const float* g_in = (const float*)d_in[4];
    const float* be_in= (const float*)d_in[5];
    const float* wl1  = (const float*)d_in[6];
    const float* bl1  = (const float*)d_in[7];
    const float* wr1  = (const float*)d_in[8];
    const float* g1   = (const float*)d_in[9];
    const float* be1  = (const float*)d_in[10];
    const float* wl2  = (const float*)d_in[11];
    const float* bl2  = (const float*)d_in[12];
    const float* wr2  = (const float*)d_in[13];
    const float* g2   = (const float*)d_in[14];
    const float* be2  = (const float*)d_in[15];
    const float* wl3  = (const float*)d_in[16];
    const float* bl3  = (const float*)d_in[17];
    const float* wr3  = (const float*)d_in[18];
    float* out = (float*)d_out;

    char* p = (char*)d_ws;
    auto alloc = [&](size_t bytes) -> void* {
        void* r = (void*)p;
        p += (bytes + 255) & ~(size_t)255;
        return r;
    };
    // zero-region: cnt + 3 sharded stats buffers (contiguous)
    int*   cnt    = (int*)alloc((size_t)N_NODES * 4);
    float* stats0 = (float*)alloc((size_t)NSHARD * SSTRIDE * 4);
    float* stats1 = (float*)alloc((size_t)NSHARD * SSTRIDE * 4);
    float* stats2 = (float*)alloc((size_t)NSHARD * SSTRIDE * 4);
    size_t zlen = (size_t)((char*)stats2 + NSHARD * SSTRIDE * 4 - (char*)cnt);

    unsigned short* bufA = (unsigned short*)alloc((size_t)N_NODES * HID * 2);
    unsigned short* bufB = (unsigned short*)alloc((size_t)N_NODES * HID * 2);
    unsigned short* bufC = (unsigned short*)alloc((size_t)N_NODES * HID * 2);
    unsigned char*  h8   = (unsigned char*)alloc((size_t)N_NODES * HID);
    unsigned short* wl1t = (unsigned short*)alloc((size_t)HID * HID * 2);
    unsigned short* wr1t = (unsigned short*)alloc((size_t)HID * HID * 2);
    unsigned short* wl2t = (unsigned short*)alloc((size_t)HID * HID * 2);
    unsigned short* wr2t = (unsigned short*)alloc((size_t)HID * HID * 2);
    unsigned short* wl3t = (unsigned short*)alloc((size_t)EMB * HID * 2);
    unsigned short* wr3t = (unsigned short*)alloc((size_t)EMB * HID * 2);
    int*   row_off    = (int*)alloc((size_t)(N_NODES + 1) * 4);
    int*   fill_pos   = (int*)alloc((size_t)N_NODES * 4);
    int*   sorted_src = (int*)alloc((size_t)N_EDGES * 4);
    int*   part       = (int*)alloc((size_t)256 * 4);
    int*   partoff    = (int*)alloc((size_t)256 * 4);

    const int* e_src = ei;
    const int* e_dst = ei + N_EDGES;

    hipMemsetAsync(cnt, 0, zlen, stream);
    k_count_wconv<<<CNT_BLKS + WCONV_BLKS, 256, 0, stream>>>(
        e_dst, cnt, wl1, wr1, wl2, wr2, wl3, wr3, wl1t, wr1t, wl2t, wr2t, wl3t, wr3t);
    k_reduce_cnt<<<N_SCAN_BLKS, 256, 0, stream>>>(cnt, part);
    k_scan_part<<<1, 256, 0, stream>>>(part, partoff, &row_off[N_NODES]);
    k_scan_final<<<N_SCAN_BLKS, 256, 0, stream>>>(cnt, partoff, row_off, fill_pos);
    k_scatter_part<<<SCAT_BLKS, 256, 0, stream>>>(e_src, e_dst, fill_pos, sorted_src);

    k_input_proj<<<IP_BLOCKS, 256, 0, stream>>>(x, w_in, b_in, bufA, stats0);
    k_bn_apply_relu<<<(N_NODES * 32 + 255) / 256, 256, 0, stream>>>(bufA, stats0, g_in, be_in, h8);

    const int GEMM_BLKS = 784;
    int aggF8_blocks = (N_NODES * 16 + 255) / 256;

    // SAGE layer 1
    k_aggregate_fp8<<<aggF8_blocks, 256, 0, stream>>>(h8, row_off, cnt, sorted_src, bufC);
    k_gemm_mfma<HID, true><<<GEMM_BLKS, 512, 0, stream>>>(bufC, wl1t, bufA, wr1t, bl1, stats1, bufB);
    k_bn_apply_relu<<<(N_NODES * 32 + 255) / 256, 256, 0, stream>>>(bufB, stats1, g1, be1, h8);

    // SAGE layer 2 (raw h2 + stats2; BN deferred into layer-3 GEMM)
    k_aggregate_fp8<<<aggF8_blocks, 256, 0, stream>>>(h8, row_off, cnt, sorted_src, bufC);
    k_gemm_mfma<HID, true><<<GEMM_BLKS, 512, 0, stream>>>(bufC, wl2t, bufB, wr2t, bl2, stats2, bufA);

    // layer-3 dual GEMM with fused BN, then out += neighbor-mean of G
    k_gemm_l3_dual<<<(N_NODES + 127) / 128, 512, 0, stream>>>(
        bufA, wl3t, wr3t, stats2, g2, be2, bl3, bufB, out);
    k_aggregate_add<<<(N_NODES * 16 + 255) / 256, 256, 0, stream>>>(bufB, row_off, cnt, sorted_src, out);
}